// Round 1
// baseline (2888.917 us; speedup 1.0000x reference)
//
#include <hip/hip_runtime.h>

#define N_USERS 100000
#define N_ITEMS 200000
#define N_NODES (N_USERS + N_ITEMS)
#define EMB     64
#define NNZ     4000000

// ---------------------------------------------------------------------------
// init: out = bufA = concat(user_table, item_table); bufB = 0
// float4-vectorized over 19.2M floats (4.8M float4s)
// ---------------------------------------------------------------------------
__global__ void init_kernel(const float* __restrict__ user_t,
                            const float* __restrict__ item_t,
                            float* __restrict__ out,
                            float* __restrict__ bufA,
                            float* __restrict__ bufB) {
    int i = blockIdx.x * blockDim.x + threadIdx.x;       // float4 index
    const int total4 = N_NODES * EMB / 4;
    if (i >= total4) return;
    int fi   = i * 4;
    int node = fi >> 6;           // /EMB
    int off  = fi & 63;           // %EMB
    float4 v;
    if (node < N_USERS)
        v = *(const float4*)(user_t + (size_t)node * EMB + off);
    else
        v = *(const float4*)(item_t + (size_t)(node - N_USERS) * EMB + off);
    *(float4*)(out  + fi) = v;
    *(float4*)(bufA + fi) = v;
    *(float4*)(bufB + fi) = make_float4(0.f, 0.f, 0.f, 0.f);
}

// ---------------------------------------------------------------------------
// spmm scatter: y[rows[e]*64 + d] += vals[e] * x[cols[e]*64 + d]
// one wave (64 lanes) per edge, lane = dim
// ---------------------------------------------------------------------------
__global__ void spmm_kernel(const int*   __restrict__ rows,
                            const int*   __restrict__ cols,
                            const float* __restrict__ vals,
                            const float* __restrict__ x,
                            float*       __restrict__ y) {
    int tid  = blockIdx.x * blockDim.x + threadIdx.x;
    int e    = tid >> 6;
    int lane = tid & 63;
    if (e >= NNZ) return;
    int   r = rows[e];
    int   c = cols[e];
    float v = vals[e];
    float xv = x[(size_t)c * EMB + lane];
    atomicAdd(&y[(size_t)r * EMB + lane], v * xv);
}

// ---------------------------------------------------------------------------
// acc: out += src ; zbuf = 0   (zbuf becomes next layer's scatter target)
// ---------------------------------------------------------------------------
__global__ void acc_zero_kernel(float* __restrict__ out,
                                const float* __restrict__ src,
                                float* __restrict__ zbuf) {
    int i = blockIdx.x * blockDim.x + threadIdx.x;       // float4 index
    const int total4 = N_NODES * EMB / 4;
    if (i >= total4) return;
    int fi = i * 4;
    float4 o = *(float4*)(out + fi);
    float4 s = *(const float4*)(src + fi);
    o.x += s.x; o.y += s.y; o.z += s.z; o.w += s.w;
    *(float4*)(out  + fi) = o;
    *(float4*)(zbuf + fi) = make_float4(0.f, 0.f, 0.f, 0.f);
}

// ---------------------------------------------------------------------------
// final: out = (out + src) * 0.25
// ---------------------------------------------------------------------------
__global__ void final_kernel(float* __restrict__ out,
                             const float* __restrict__ src) {
    int i = blockIdx.x * blockDim.x + threadIdx.x;       // float4 index
    const int total4 = N_NODES * EMB / 4;
    if (i >= total4) return;
    int fi = i * 4;
    float4 o = *(float4*)(out + fi);
    float4 s = *(const float4*)(src + fi);
    o.x = (o.x + s.x) * 0.25f;
    o.y = (o.y + s.y) * 0.25f;
    o.z = (o.z + s.z) * 0.25f;
    o.w = (o.w + s.w) * 0.25f;
    *(float4*)(out + fi) = o;
}

extern "C" void kernel_launch(void* const* d_in, const int* in_sizes, int n_in,
                              void* d_out, int out_size, void* d_ws, size_t ws_size,
                              hipStream_t stream) {
    const float* user_t = (const float*)d_in[0];
    const float* item_t = (const float*)d_in[1];
    const int*   rows   = (const int*)d_in[2];
    const int*   cols   = (const int*)d_in[3];
    const float* vals   = (const float*)d_in[4];
    float* out = (float*)d_out;

    float* bufA = (float*)d_ws;                              // 76.8 MB
    float* bufB = bufA + (size_t)N_NODES * EMB;              // 76.8 MB

    const int total4     = N_NODES * EMB / 4;                // 4.8M
    const int ew_blocks  = (total4 + 255) / 256;
    const int spmm_blocks = (int)(((size_t)NNZ * 64 + 255) / 256);  // 1,000,000

    // out = bufA = emb ; bufB = 0
    init_kernel<<<ew_blocks, 256, 0, stream>>>(user_t, item_t, out, bufA, bufB);

    // layer 1: A -> B ; out += B ; A = 0
    spmm_kernel<<<spmm_blocks, 256, 0, stream>>>(rows, cols, vals, bufA, bufB);
    acc_zero_kernel<<<ew_blocks, 256, 0, stream>>>(out, bufB, bufA);

    // layer 2: B -> A ; out += A ; B = 0
    spmm_kernel<<<spmm_blocks, 256, 0, stream>>>(rows, cols, vals, bufB, bufA);
    acc_zero_kernel<<<ew_blocks, 256, 0, stream>>>(out, bufA, bufB);

    // layer 3: A -> B ; out = (out + B) / 4
    spmm_kernel<<<spmm_blocks, 256, 0, stream>>>(rows, cols, vals, bufA, bufB);
    final_kernel<<<ew_blocks, 256, 0, stream>>>(out, bufB);
}

// Round 2
// 1351.184 us; speedup vs baseline: 2.1381x; 2.1381x over previous
//
#include <hip/hip_runtime.h>

#define N_USERS 100000
#define N_ITEMS 200000
#define N_NODES (N_USERS + N_ITEMS)
#define EMB     64
#define NNZ     4000000

#define SCAN_BLOCK 256
#define SCAN_ITEMS 4
#define SCAN_TILE  (SCAN_BLOCK * SCAN_ITEMS)              // 1024
#define NUM_TILES  ((N_NODES + SCAN_TILE - 1) / SCAN_TILE) // 293

// ===========================================================================
// CSR-build path
// ===========================================================================

// histogram of row degrees
__global__ void hist_kernel(const int* __restrict__ rows, int* __restrict__ cnt) {
    int e = blockIdx.x * blockDim.x + threadIdx.x;
    if (e < NNZ) atomicAdd(&cnt[rows[e]], 1);
}

// per-tile exclusive scan; tile totals to tile_sums
__global__ void scan1_kernel(const int* __restrict__ cnt,
                             int* __restrict__ excl,
                             int* __restrict__ tile_sums) {
    __shared__ int s[SCAN_BLOCK];
    int tid  = threadIdx.x;
    int base = blockIdx.x * SCAN_TILE + tid * SCAN_ITEMS;
    int v[SCAN_ITEMS];
    int sum = 0;
#pragma unroll
    for (int j = 0; j < SCAN_ITEMS; j++) {
        int idx = base + j;
        v[j] = (idx < N_NODES) ? cnt[idx] : 0;
        sum += v[j];
    }
    s[tid] = sum;
    __syncthreads();
    for (int off = 1; off < SCAN_BLOCK; off <<= 1) {
        int t = 0;
        if (tid >= off) t = s[tid - off];
        __syncthreads();
        if (tid >= off) s[tid] += t;
        __syncthreads();
    }
    int run = s[tid] - sum;   // exclusive prefix for this thread's first element
#pragma unroll
    for (int j = 0; j < SCAN_ITEMS; j++) {
        int idx = base + j;
        if (idx < N_NODES) excl[idx] = run;
        run += v[j];
    }
    if (tid == SCAN_BLOCK - 1) tile_sums[blockIdx.x] = s[tid];
}

// exclusive scan of tile sums (NUM_TILES <= 512), single block
__global__ void scan2_kernel(int* __restrict__ tile_sums) {
    __shared__ int s[512];
    int tid = threadIdx.x;
    int v = (tid < NUM_TILES) ? tile_sums[tid] : 0;
    s[tid] = v;
    __syncthreads();
    for (int off = 1; off < 512; off <<= 1) {
        int t = 0;
        if (tid >= off) t = s[tid - off];
        __syncthreads();
        if (tid >= off) s[tid] += t;
        __syncthreads();
    }
    if (tid < NUM_TILES) tile_sums[tid] = s[tid] - v;  // exclusive
}

// add tile offsets in place -> row_ptr; copy to cursor; close row_ptr
__global__ void scan3_kernel(int* __restrict__ row_ptr,
                             const int* __restrict__ tile_sums,
                             int* __restrict__ cursor) {
    int i = blockIdx.x * blockDim.x + threadIdx.x;
    if (i < N_NODES) {
        int v = row_ptr[i] + tile_sums[i / SCAN_TILE];
        row_ptr[i] = v;
        cursor[i]  = v;
    }
    if (i == 0) row_ptr[N_NODES] = NNZ;
}

// scatter edges into row-grouped order as (col_bits, val) pairs
__global__ void scatter_kernel(const int*   __restrict__ rows,
                               const int*   __restrict__ cols,
                               const float* __restrict__ vals,
                               int*         __restrict__ cursor,
                               float2*      __restrict__ edges) {
    int e = blockIdx.x * blockDim.x + threadIdx.x;
    if (e >= NNZ) return;
    int r   = rows[e];
    int pos = atomicAdd(&cursor[r], 1);
    edges[pos] = make_float2(__int_as_float(cols[e]), vals[e]);
}

// out = bufA = concat(user, item)
__global__ void init2_kernel(const float* __restrict__ user_t,
                             const float* __restrict__ item_t,
                             float* __restrict__ out,
                             float* __restrict__ bufA) {
    int i = blockIdx.x * blockDim.x + threadIdx.x;       // float4 index
    const int total4 = N_NODES * EMB / 4;
    if (i >= total4) return;
    int fi   = i * 4;
    int node = fi >> 6;
    int off  = fi & 63;
    float4 v;
    if (node < N_USERS)
        v = *(const float4*)(user_t + (size_t)node * EMB + off);
    else
        v = *(const float4*)(item_t + (size_t)(node - N_USERS) * EMB + off);
    *(float4*)(out  + fi) = v;
    *(float4*)(bufA + fi) = v;
}

// one wave per row: y[row] = sum_e val*x[col]; out[row] = (out[row]+y)*scale
__global__ void spmm_csr_kernel(const int*    __restrict__ row_ptr,
                                const float2* __restrict__ edges,
                                const float*  __restrict__ x,
                                float*        __restrict__ y,
                                float*        __restrict__ out,
                                float scale) {
    int t    = blockIdx.x * blockDim.x + threadIdx.x;
    int row  = t >> 6;
    int lane = t & 63;
    if (row >= N_NODES) return;
    int beg = row_ptr[row];
    int end = row_ptr[row + 1];
    float acc = 0.f;
    int i = beg;
    for (; i + 1 < end; i += 2) {
        float2 e0 = edges[i];
        float2 e1 = edges[i + 1];
        int c0 = __float_as_int(e0.x);
        int c1 = __float_as_int(e1.x);
        float x0 = x[(size_t)c0 * EMB + lane];
        float x1 = x[(size_t)c1 * EMB + lane];
        acc += e0.y * x0 + e1.y * x1;
    }
    if (i < end) {
        float2 e0 = edges[i];
        acc += e0.y * x[(size_t)__float_as_int(e0.x) * EMB + lane];
    }
    size_t o = (size_t)row * EMB + lane;
    y[o] = acc;
    out[o] = (out[o] + acc) * scale;
}

// ===========================================================================
// Fallback atomic-scatter path (R1) — used only if ws_size too small
// ===========================================================================
__global__ void init_kernel(const float* __restrict__ user_t,
                            const float* __restrict__ item_t,
                            float* __restrict__ out,
                            float* __restrict__ bufA,
                            float* __restrict__ bufB) {
    int i = blockIdx.x * blockDim.x + threadIdx.x;
    const int total4 = N_NODES * EMB / 4;
    if (i >= total4) return;
    int fi   = i * 4;
    int node = fi >> 6;
    int off  = fi & 63;
    float4 v;
    if (node < N_USERS)
        v = *(const float4*)(user_t + (size_t)node * EMB + off);
    else
        v = *(const float4*)(item_t + (size_t)(node - N_USERS) * EMB + off);
    *(float4*)(out  + fi) = v;
    *(float4*)(bufA + fi) = v;
    *(float4*)(bufB + fi) = make_float4(0.f, 0.f, 0.f, 0.f);
}

__global__ void spmm_kernel(const int*   __restrict__ rows,
                            const int*   __restrict__ cols,
                            const float* __restrict__ vals,
                            const float* __restrict__ x,
                            float*       __restrict__ y) {
    int tid  = blockIdx.x * blockDim.x + threadIdx.x;
    int e    = tid >> 6;
    int lane = tid & 63;
    if (e >= NNZ) return;
    int   r = rows[e];
    int   c = cols[e];
    float v = vals[e];
    atomicAdd(&y[(size_t)r * EMB + lane], v * x[(size_t)c * EMB + lane]);
}

__global__ void acc_zero_kernel(float* __restrict__ out,
                                const float* __restrict__ src,
                                float* __restrict__ zbuf) {
    int i = blockIdx.x * blockDim.x + threadIdx.x;
    const int total4 = N_NODES * EMB / 4;
    if (i >= total4) return;
    int fi = i * 4;
    float4 o = *(float4*)(out + fi);
    float4 s = *(const float4*)(src + fi);
    o.x += s.x; o.y += s.y; o.z += s.z; o.w += s.w;
    *(float4*)(out  + fi) = o;
    *(float4*)(zbuf + fi) = make_float4(0.f, 0.f, 0.f, 0.f);
}

__global__ void final_kernel(float* __restrict__ out,
                             const float* __restrict__ src) {
    int i = blockIdx.x * blockDim.x + threadIdx.x;
    const int total4 = N_NODES * EMB / 4;
    if (i >= total4) return;
    int fi = i * 4;
    float4 o = *(float4*)(out + fi);
    float4 s = *(const float4*)(src + fi);
    o.x = (o.x + s.x) * 0.25f;
    o.y = (o.y + s.y) * 0.25f;
    o.z = (o.z + s.z) * 0.25f;
    o.w = (o.w + s.w) * 0.25f;
    *(float4*)(out + fi) = o;
}

// ===========================================================================
extern "C" void kernel_launch(void* const* d_in, const int* in_sizes, int n_in,
                              void* d_out, int out_size, void* d_ws, size_t ws_size,
                              hipStream_t stream) {
    const float* user_t = (const float*)d_in[0];
    const float* item_t = (const float*)d_in[1];
    const int*   rows   = (const int*)d_in[2];
    const int*   cols   = (const int*)d_in[3];
    const float* vals   = (const float*)d_in[4];
    float* out = (float*)d_out;

    const size_t emb_elems = (size_t)N_NODES * EMB;          // 19.2M floats
    const int total4     = N_NODES * EMB / 4;
    const int ew_blocks  = (total4 + 255) / 256;

    // ---- workspace layout for CSR path ----
    char* p = (char*)d_ws;
    float*  bufA      = (float*)p;            p += emb_elems * 4;          // 76.8 MB
    float*  bufB      = (float*)p;            p += emb_elems * 4;          // 76.8 MB
    float2* edges     = (float2*)p;           p += (size_t)NNZ * 8;        // 32 MB
    int*    row_ptr   = (int*)p;              p += (size_t)(N_NODES + 1) * 4;
    int*    cursor    = (int*)p;              p += (size_t)N_NODES * 4;
    int*    cnt       = (int*)p;              p += (size_t)N_NODES * 4;
    int*    tile_sums = (int*)p;              p += (size_t)NUM_TILES * 4;
    size_t need = (size_t)(p - (char*)d_ws);

    if (ws_size >= need) {
        // ---- CSR build ----
        hipMemsetAsync(cnt, 0, (size_t)N_NODES * 4, stream);
        hist_kernel<<<(NNZ + 255) / 256, 256, 0, stream>>>(rows, cnt);
        scan1_kernel<<<NUM_TILES, SCAN_BLOCK, 0, stream>>>(cnt, row_ptr, tile_sums);
        scan2_kernel<<<1, 512, 0, stream>>>(tile_sums);
        scan3_kernel<<<(N_NODES + 255) / 256, 256, 0, stream>>>(row_ptr, tile_sums, cursor);
        scatter_kernel<<<(NNZ + 255) / 256, 256, 0, stream>>>(rows, cols, vals, cursor, edges);

        // ---- init + 3 fused spmm layers ----
        init2_kernel<<<ew_blocks, 256, 0, stream>>>(user_t, item_t, out, bufA);

        const int spmm_blocks = (int)(((size_t)N_NODES * 64 + 255) / 256);  // 75000
        spmm_csr_kernel<<<spmm_blocks, 256, 0, stream>>>(row_ptr, edges, bufA, bufB, out, 1.0f);
        spmm_csr_kernel<<<spmm_blocks, 256, 0, stream>>>(row_ptr, edges, bufB, bufA, out, 1.0f);
        spmm_csr_kernel<<<spmm_blocks, 256, 0, stream>>>(row_ptr, edges, bufA, bufB, out, 0.25f);
    } else {
        // ---- fallback: R1 atomic path ----
        const int spmm_blocks = (int)(((size_t)NNZ * 64 + 255) / 256);
        init_kernel<<<ew_blocks, 256, 0, stream>>>(user_t, item_t, out, bufA, bufB);
        spmm_kernel<<<spmm_blocks, 256, 0, stream>>>(rows, cols, vals, bufA, bufB);
        acc_zero_kernel<<<ew_blocks, 256, 0, stream>>>(out, bufB, bufA);
        spmm_kernel<<<spmm_blocks, 256, 0, stream>>>(rows, cols, vals, bufB, bufA);
        acc_zero_kernel<<<ew_blocks, 256, 0, stream>>>(out, bufA, bufB);
        spmm_kernel<<<spmm_blocks, 256, 0, stream>>>(rows, cols, vals, bufA, bufB);
        final_kernel<<<ew_blocks, 256, 0, stream>>>(out, bufB);
    }
}

// Round 3
// 1229.203 us; speedup vs baseline: 2.3502x; 1.0992x over previous
//
#include <hip/hip_runtime.h>

#define N_USERS 100000
#define N_ITEMS 200000
#define N_NODES (N_USERS + N_ITEMS)
#define EMB     64
#define NNZ     4000000

#define SCAN_BLOCK 256
#define SCAN_ITEMS 4
#define SCAN_TILE  (SCAN_BLOCK * SCAN_ITEMS)               // 1024
#define NUM_TILES  ((N_NODES + SCAN_TILE - 1) / SCAN_TILE) // 293

#define BSHIFT 8
#define BROWS  (1 << BSHIFT)                               // 256 rows / bucket
#define NBUCK  ((N_NODES + BROWS - 1) >> BSHIFT)           // 1172

// ===========================================================================
// CSR build
// ===========================================================================
__global__ void hist_kernel(const int* __restrict__ rows, int* __restrict__ cnt) {
    int e = blockIdx.x * blockDim.x + threadIdx.x;
    if (e < NNZ) atomicAdd(&cnt[rows[e]], 1);
}

__global__ void scan1_kernel(const int* __restrict__ cnt,
                             int* __restrict__ excl,
                             int* __restrict__ tile_sums) {
    __shared__ int s[SCAN_BLOCK];
    int tid  = threadIdx.x;
    int base = blockIdx.x * SCAN_TILE + tid * SCAN_ITEMS;
    int v[SCAN_ITEMS];
    int sum = 0;
#pragma unroll
    for (int j = 0; j < SCAN_ITEMS; j++) {
        int idx = base + j;
        v[j] = (idx < N_NODES) ? cnt[idx] : 0;
        sum += v[j];
    }
    s[tid] = sum;
    __syncthreads();
    for (int off = 1; off < SCAN_BLOCK; off <<= 1) {
        int t = 0;
        if (tid >= off) t = s[tid - off];
        __syncthreads();
        if (tid >= off) s[tid] += t;
        __syncthreads();
    }
    int run = s[tid] - sum;
#pragma unroll
    for (int j = 0; j < SCAN_ITEMS; j++) {
        int idx = base + j;
        if (idx < N_NODES) excl[idx] = run;
        run += v[j];
    }
    if (tid == SCAN_BLOCK - 1) tile_sums[blockIdx.x] = s[tid];
}

__global__ void scan2_kernel(int* __restrict__ tile_sums) {
    __shared__ int s[512];
    int tid = threadIdx.x;
    int v = (tid < NUM_TILES) ? tile_sums[tid] : 0;
    s[tid] = v;
    __syncthreads();
    for (int off = 1; off < 512; off <<= 1) {
        int t = 0;
        if (tid >= off) t = s[tid - off];
        __syncthreads();
        if (tid >= off) s[tid] += t;
        __syncthreads();
    }
    if (tid < NUM_TILES) tile_sums[tid] = s[tid] - v;
}

__global__ void scan3_kernel(int* __restrict__ row_ptr,
                             const int* __restrict__ tile_sums,
                             int* __restrict__ cursor) {
    int i = blockIdx.x * blockDim.x + threadIdx.x;
    if (i < N_NODES) {
        int v = row_ptr[i] + tile_sums[i / SCAN_TILE];
        row_ptr[i] = v;
        cursor[i]  = v;
    }
    if (i == 0) row_ptr[N_NODES] = NNZ;
}

// bucket cursors (64B-padded) = CSR offset of bucket start
__global__ void binit_kernel(const int* __restrict__ row_ptr, int* __restrict__ bcur) {
    int b = blockIdx.x * blockDim.x + threadIdx.x;
    if (b < NBUCK) bcur[b * 16] = row_ptr[b << BSHIFT];
}

// pass 1: append edges into their row-bucket (sequential streams per bucket)
__global__ void bucket_kernel(const int*   __restrict__ rows,
                              const int*   __restrict__ cols,
                              const float* __restrict__ vals,
                              int*         __restrict__ bcur,
                              float2*      __restrict__ pay,
                              unsigned short* __restrict__ rlo) {
    int e = blockIdx.x * blockDim.x + threadIdx.x;
    if (e >= NNZ) return;
    int r   = rows[e];
    int pos = atomicAdd(&bcur[(r >> BSHIFT) * 16], 1);
    pay[pos] = make_float2(__int_as_float(cols[e]), vals[e]);
    rlo[pos] = (unsigned short)(r & (BROWS - 1));
}

// pass 2: one block per bucket; place edges at final CSR positions
// (random writes confined to the bucket's ~27 KB window -> L2-resident)
__global__ void place_kernel(const int*    __restrict__ row_ptr,
                             const float2* __restrict__ pay,
                             const unsigned short* __restrict__ rlo,
                             int*          __restrict__ cursor,
                             float2*       __restrict__ edges) {
    int b   = blockIdx.x;
    int beg = row_ptr[b << BSHIFT];
    int endRow = (b + 1) << BSHIFT;
    if (endRow > N_NODES) endRow = N_NODES;
    int end = row_ptr[endRow];
    for (int i = beg + threadIdx.x; i < end; i += blockDim.x) {
        float2 p = pay[i];
        int r    = (b << BSHIFT) + rlo[i];
        int pos  = atomicAdd(&cursor[r], 1);
        edges[pos] = p;
    }
}

// out = bufA = concat(user, item)
__global__ void init2_kernel(const float* __restrict__ user_t,
                             const float* __restrict__ item_t,
                             float* __restrict__ out,
                             float* __restrict__ bufA) {
    int i = blockIdx.x * blockDim.x + threadIdx.x;
    const int total4 = N_NODES * EMB / 4;
    if (i >= total4) return;
    int fi   = i * 4;
    int node = fi >> 6;
    int off  = fi & 63;
    float4 v;
    if (node < N_USERS)
        v = *(const float4*)(user_t + (size_t)node * EMB + off);
    else
        v = *(const float4*)(item_t + (size_t)(node - N_USERS) * EMB + off);
    *(float4*)(out  + fi) = v;
    *(float4*)(bufA + fi) = v;
}

// SpMM: 4 rows per wave; lane = (quarter q = row, slot s = dims 4s..4s+3)
__global__ void spmm4_kernel(const int*    __restrict__ rp,
                             const float2* __restrict__ edges,
                             const float*  __restrict__ x,
                             float*        __restrict__ y,
                             float*        __restrict__ out,
                             float scale) {
    int t    = blockIdx.x * blockDim.x + threadIdx.x;
    int wid  = t >> 6;
    int lane = t & 63;
    int q    = lane >> 4;
    int s    = lane & 15;
    int row  = (wid << 2) + q;
    if (row >= N_NODES) return;
    int i   = rp[row];
    int end = rp[row + 1];
    float4 acc = make_float4(0.f, 0.f, 0.f, 0.f);
    for (; i + 1 < end; i += 2) {
        float2 e0 = edges[i];
        float2 e1 = edges[i + 1];
        float4 a = *(const float4*)(x + ((size_t)__float_as_int(e0.x) << 6) + (s << 2));
        float4 b = *(const float4*)(x + ((size_t)__float_as_int(e1.x) << 6) + (s << 2));
        acc.x += e0.y * a.x + e1.y * b.x;
        acc.y += e0.y * a.y + e1.y * b.y;
        acc.z += e0.y * a.z + e1.y * b.z;
        acc.w += e0.y * a.w + e1.y * b.w;
    }
    if (i < end) {
        float2 e0 = edges[i];
        float4 a = *(const float4*)(x + ((size_t)__float_as_int(e0.x) << 6) + (s << 2));
        acc.x += e0.y * a.x;
        acc.y += e0.y * a.y;
        acc.z += e0.y * a.z;
        acc.w += e0.y * a.w;
    }
    size_t o = ((size_t)row << 6) + (s << 2);
    *(float4*)(y + o) = acc;
    float4 ov = *(float4*)(out + o);
    ov.x = (ov.x + acc.x) * scale;
    ov.y = (ov.y + acc.y) * scale;
    ov.z = (ov.z + acc.z) * scale;
    ov.w = (ov.w + acc.w) * scale;
    *(float4*)(out + o) = ov;
}

// ===========================================================================
// Fallback atomic path (tiny ws only)
// ===========================================================================
__global__ void init_kernel(const float* __restrict__ user_t,
                            const float* __restrict__ item_t,
                            float* __restrict__ out,
                            float* __restrict__ bufA,
                            float* __restrict__ bufB) {
    int i = blockIdx.x * blockDim.x + threadIdx.x;
    const int total4 = N_NODES * EMB / 4;
    if (i >= total4) return;
    int fi   = i * 4;
    int node = fi >> 6;
    int off  = fi & 63;
    float4 v;
    if (node < N_USERS)
        v = *(const float4*)(user_t + (size_t)node * EMB + off);
    else
        v = *(const float4*)(item_t + (size_t)(node - N_USERS) * EMB + off);
    *(float4*)(out  + fi) = v;
    *(float4*)(bufA + fi) = v;
    *(float4*)(bufB + fi) = make_float4(0.f, 0.f, 0.f, 0.f);
}

__global__ void spmm_kernel(const int*   __restrict__ rows,
                            const int*   __restrict__ cols,
                            const float* __restrict__ vals,
                            const float* __restrict__ x,
                            float*       __restrict__ y) {
    int tid  = blockIdx.x * blockDim.x + threadIdx.x;
    int e    = tid >> 6;
    int lane = tid & 63;
    if (e >= NNZ) return;
    atomicAdd(&y[(size_t)rows[e] * EMB + lane], vals[e] * x[(size_t)cols[e] * EMB + lane]);
}

__global__ void acc_zero_kernel(float* __restrict__ out,
                                const float* __restrict__ src,
                                float* __restrict__ zbuf) {
    int i = blockIdx.x * blockDim.x + threadIdx.x;
    const int total4 = N_NODES * EMB / 4;
    if (i >= total4) return;
    int fi = i * 4;
    float4 o = *(float4*)(out + fi);
    float4 s = *(const float4*)(src + fi);
    o.x += s.x; o.y += s.y; o.z += s.z; o.w += s.w;
    *(float4*)(out  + fi) = o;
    *(float4*)(zbuf + fi) = make_float4(0.f, 0.f, 0.f, 0.f);
}

__global__ void final_kernel(float* __restrict__ out,
                             const float* __restrict__ src) {
    int i = blockIdx.x * blockDim.x + threadIdx.x;
    const int total4 = N_NODES * EMB / 4;
    if (i >= total4) return;
    int fi = i * 4;
    float4 o = *(float4*)(out + fi);
    float4 s = *(const float4*)(src + fi);
    o.x = (o.x + s.x) * 0.25f;
    o.y = (o.y + s.y) * 0.25f;
    o.z = (o.z + s.z) * 0.25f;
    o.w = (o.w + s.w) * 0.25f;
    *(float4*)(out + fi) = o;
}

// ===========================================================================
extern "C" void kernel_launch(void* const* d_in, const int* in_sizes, int n_in,
                              void* d_out, int out_size, void* d_ws, size_t ws_size,
                              hipStream_t stream) {
    const float* user_t = (const float*)d_in[0];
    const float* item_t = (const float*)d_in[1];
    const int*   rows   = (const int*)d_in[2];
    const int*   cols   = (const int*)d_in[3];
    const float* vals   = (const float*)d_in[4];
    float* out = (float*)d_out;

    const size_t emb_elems = (size_t)N_NODES * EMB;
    const int total4    = N_NODES * EMB / 4;
    const int ew_blocks = (total4 + 255) / 256;

    // ---- workspace layout (same footprint as R2) ----
    char* p = (char*)d_ws;
    float*  bufA      = (float*)p;  p += emb_elems * 4;           // 76.8 MB
    float*  bufB      = (float*)p;  p += emb_elems * 4;           // 76.8 MB
    float2* edges     = (float2*)p; p += (size_t)NNZ * 8;         // 32 MB
    int*    row_ptr   = (int*)p;    p += (size_t)(N_NODES + 1) * 4;
    int*    cursor    = (int*)p;    p += (size_t)N_NODES * 4;
    int*    cnt       = (int*)p;    p += (size_t)N_NODES * 4;
    int*    tile_sums = (int*)p;    p += (size_t)NUM_TILES * 4;
    size_t need = (size_t)(p - (char*)d_ws);

    // aliases: pay/rlo live in bufB (dead until first spmm); bcur lives in cnt
    // (cnt dead after scan1).
    float2*         pay  = (float2*)bufB;                         // 32 MB
    unsigned short* rlo  = (unsigned short*)(bufB + (size_t)NNZ * 2); // 8 MB
    int*            bcur = cnt;                                   // 75 KB used

    if (ws_size >= need) {
        hipMemsetAsync(cnt, 0, (size_t)N_NODES * 4, stream);
        hist_kernel <<<(NNZ + 255) / 256, 256, 0, stream>>>(rows, cnt);
        scan1_kernel<<<NUM_TILES, SCAN_BLOCK, 0, stream>>>(cnt, row_ptr, tile_sums);
        scan2_kernel<<<1, 512, 0, stream>>>(tile_sums);
        scan3_kernel<<<(N_NODES + 255) / 256, 256, 0, stream>>>(row_ptr, tile_sums, cursor);
        binit_kernel<<<(NBUCK + 255) / 256, 256, 0, stream>>>(row_ptr, bcur);
        bucket_kernel<<<(NNZ + 255) / 256, 256, 0, stream>>>(rows, cols, vals, bcur, pay, rlo);
        place_kernel<<<NBUCK, 256, 0, stream>>>(row_ptr, pay, rlo, cursor, edges);

        init2_kernel<<<ew_blocks, 256, 0, stream>>>(user_t, item_t, out, bufA);

        const int spmm_blocks = (int)(((size_t)N_NODES / 4 * 64 + 255) / 256); // 18750
        spmm4_kernel<<<spmm_blocks, 256, 0, stream>>>(row_ptr, edges, bufA, bufB, out, 1.0f);
        spmm4_kernel<<<spmm_blocks, 256, 0, stream>>>(row_ptr, edges, bufB, bufA, out, 1.0f);
        spmm4_kernel<<<spmm_blocks, 256, 0, stream>>>(row_ptr, edges, bufA, bufB, out, 0.25f);
    } else {
        const int spmm_blocks = (int)(((size_t)NNZ * 64 + 255) / 256);
        init_kernel<<<ew_blocks, 256, 0, stream>>>(user_t, item_t, out, bufA, bufB);
        spmm_kernel<<<spmm_blocks, 256, 0, stream>>>(rows, cols, vals, bufA, bufB);
        acc_zero_kernel<<<ew_blocks, 256, 0, stream>>>(out, bufB, bufA);
        spmm_kernel<<<spmm_blocks, 256, 0, stream>>>(rows, cols, vals, bufB, bufA);
        acc_zero_kernel<<<ew_blocks, 256, 0, stream>>>(out, bufA, bufB);
        spmm_kernel<<<spmm_blocks, 256, 0, stream>>>(rows, cols, vals, bufA, bufB);
        final_kernel<<<ew_blocks, 256, 0, stream>>>(out, bufB);
    }
}